// Round 2
// baseline (10116.386 us; speedup 1.0000x reference)
//
#include <hip/hip_runtime.h>
#include <cstdint>
#include <cmath>
#include <cstring>

// ---------------------------------------------------------------------------
// Problem constants
// ---------------------------------------------------------------------------
#define D16    16
#define CH     128
#define NBATCH 256
#define NSP    64
#define NRBF   32
#define NKK    50          // multiplicity slots: 33 (order3) + 13 (order2) + 4 (order1)
#define NT3    816         // sorted triples a0<=a1<=a2 in [0,16)
#define NT2    136         // sorted pairs
#define LD3    160         // padded row stride for Usym3 (149 cols used)
#define LD2    64          // padded row stride for Usym2 (59 cols used)
#define U3_FLOATS (NT3*LD3)
#define U2_FLOATS (NT2*LD2)
#define U1_FLOATS 256
#define U_TOTAL   (U3_FLOATS+U2_FLOATS+U1_FLOATS)

__device__ float g_U[U_TOTAL];
__device__ float g_ws[NSP*NKK*CH];

__device__ __constant__ int8_t KK_ARR[NKK] = {
  0,0,0,0,0, 1,1,1,1,1,1,1,1, 2,2,2,2,2,2,2,2,2,2, 3,3,3,3,3,3,3,3,3,3,
  4,4, 5,5,5, 6,6,6,6, 7,7,7,7, 8,9,10,11 };
__device__ __constant__ int8_t KK_K[NKK] = {
  0,1,2,3,4, 0,1,2,3,4,5,6,7, 0,1,2,3,4,5,6,7,8,9, 0,1,2,3,4,5,6,7,8,9,
  0,1, 0,1,2, 0,1,2,3, 0,1,2,3, 0,0,0,0 };
__device__ __constant__ int8_t ARR_MUL[12] = {5,8,10,10, 2,3,4,4, 1,1,1,1};

struct WPtrs { const float* p[12]; };

// ---------------------------------------------------------------------------
// Kernel A: ws[s][kk][c] = sum_e embed[s][e]*W[e][k][c]
// ---------------------------------------------------------------------------
__global__ void weights_kernel(const float* __restrict__ embed, WPtrs wp) {
  int kk = blockIdx.x;
  int s  = blockIdx.y;
  int c  = threadIdx.x;
  int ai = KK_ARR[kk];
  int k  = KK_K[kk];
  int mul = ARR_MUL[ai];
  const float* __restrict__ W = wp.p[ai];
  float a = 0.f;
  #pragma unroll 8
  for (int e = 0; e < NRBF; ++e)
    a = fmaf(embed[s*NRBF + e], W[(e*mul + k)*CH + c], a);
  g_ws[(s*NKK + kk)*CH + c] = a;
}

// ---------------------------------------------------------------------------
// Column map: global col index (0..223) -> (kk, output i)
// cols 0..148 = U3 (0e:0-4, 1o:5-28, 2e:29-78, 3o:79-148)
// cols 149..207 = U2 (0e:+0-1, 1o:+2-10, 2e:+11-30, 3o:+31-58)
// cols 208..223 = U1
// ---------------------------------------------------------------------------
__device__ __forceinline__ void colmap(int cc, int& kk, int& ii) {
  if (cc < 149) {
    if (cc < 5)       { kk = cc;               ii = 0; }
    else if (cc < 29) { int r = cc - 5;  kk = 5  + r/3; ii = 1 + r%3; }
    else if (cc < 79) { int r = cc - 29; kk = 13 + r/5; ii = 4 + r%5; }
    else              { int r = cc - 79; kk = 23 + r/7; ii = 9 + r%7; }
  } else if (cc < 208) {
    int j = cc - 149;
    if (j < 2)        { kk = 33 + j;           ii = 0; }
    else if (j < 11)  { int r = j - 2;  kk = 35 + r/3; ii = 1 + r%3; }
    else if (j < 31)  { int r = j - 11; kk = 38 + r/5; ii = 4 + r%5; }
    else              { int r = j - 31; kk = 42 + r/7; ii = 9 + r%7; }
  } else {
    int j = cc - 208;
    if (j < 1)        { kk = 46; ii = 0; }
    else if (j < 4)   { kk = 47; ii = 1 + (j-1); }
    else if (j < 9)   { kk = 48; ii = 4 + (j-4); }
    else              { kk = 49; ii = 9 + (j-9); }
  }
}

// ---------------------------------------------------------------------------
// Sweeps: nested sorted-index loops; 1 ds_read + NC fma per monomial.
// All loop counters / U addresses are wave-uniform -> scalar loads.
// ---------------------------------------------------------------------------
template<int NC>
__device__ __forceinline__ void sweep3_run(const float* __restrict__ U3b,
                                           const float* __restrict__ xr,
                                           float* __restrict__ acc) {
  #pragma unroll
  for (int j = 0; j < NC; ++j) acc[j] = 0.f;
  int uoff = 0;
  for (int a0 = 0; a0 < D16; ++a0) {
    float x0 = xr[a0];
    for (int a1 = a0; a1 < D16; ++a1) {
      float p = x0 * xr[a1];
      for (int a2 = a1; a2 < D16; ++a2) {
        float ft = p * xr[a2];
        const float* __restrict__ row = U3b + uoff;
        #pragma unroll
        for (int j = 0; j < NC; ++j) acc[j] = fmaf(row[j], ft, acc[j]);
        uoff += LD3;
      }
    }
  }
}

template<int NC>
__device__ __forceinline__ void sweep2_run(const float* __restrict__ U2b,
                                           const float* __restrict__ xr,
                                           float* __restrict__ acc) {
  #pragma unroll
  for (int j = 0; j < NC; ++j) acc[j] = 0.f;
  int uoff = 0;
  for (int a0 = 0; a0 < D16; ++a0) {
    float x0 = xr[a0];
    for (int a1 = a0; a1 < D16; ++a1) {
      float ft = x0 * xr[a1];
      const float* __restrict__ row = U2b + uoff;
      #pragma unroll
      for (int j = 0; j < NC; ++j) acc[j] = fmaf(row[j], ft, acc[j]);
      uoff += LD2;
    }
  }
}

template<int NC>
__device__ __forceinline__ void fold_run(int cc0, const float* __restrict__ acc,
                                         const float* __restrict__ wsc,
                                         float* __restrict__ osl) {
  #pragma unroll
  for (int j = 0; j < NC; ++j) {
    int kk, ii; colmap(cc0 + j, kk, ii);
    float w = wsc[kk * CH];
    osl[ii] += w * acc[j];
  }
}

// ---------------------------------------------------------------------------
// Main kernel: block = (b, channel-half). 512 thr = 8 wave-slices x 64 chans.
// Each wave owns a contiguous column slice of the 224-col space.
// ---------------------------------------------------------------------------
__global__ __launch_bounds__(512) void main_kernel(const float* __restrict__ x,
                                                   const int* __restrict__ index,
                                                   float* __restrict__ out) {
  __shared__ float xl[64 * 17];
  __shared__ float osum[8 * 64 * 17];

  int tid   = threadIdx.x;
  int slice = __builtin_amdgcn_readfirstlane(tid >> 6);  // wave id, uniform
  int c_l   = tid & 63;
  int b     = blockIdx.x;
  int chalf = blockIdx.y;
  int c_g   = chalf * 64 + c_l;
  int s     = index[b];

  // stage x[b, c_g, 0:16] into LDS (stride 17)
  if (tid < 256) {
    int cl = tid >> 2, q = tid & 3;
    float4 v = *(const float4*)(x + ((size_t)(b*CH + chalf*64 + cl)*D16) + q*4);
    xl[cl*17 + q*4 + 0] = v.x; xl[cl*17 + q*4 + 1] = v.y;
    xl[cl*17 + q*4 + 2] = v.z; xl[cl*17 + q*4 + 3] = v.w;
  }
  // zero my osum slot
  float* osl = &osum[(slice*64 + c_l)*17];
  #pragma unroll
  for (int i = 0; i < 17; ++i) osl[i] = 0.f;
  __syncthreads();

  const float* xr  = xl + c_l*17;
  const float* wsc = g_ws + (size_t)(s*NKK)*CH + c_g;
  const float* U3  = g_U;
  const float* U2  = g_U + U3_FLOATS;
  const float* U1  = g_U + U3_FLOATS + U2_FLOATS;

  // ---- phase 1: U3, 149 cols: slices 0-4 get 19, slices 5-7 get 18 ----
  {
    int cb = (slice < 5) ? slice*19 : 95 + (slice-5)*18;
    cb = __builtin_amdgcn_readfirstlane(cb);
    if (slice < 5) {
      float acc[19]; sweep3_run<19>(U3 + cb, xr, acc); fold_run<19>(cb, acc, wsc, osl);
    } else {
      float acc[18]; sweep3_run<18>(U3 + cb, xr, acc); fold_run<18>(cb, acc, wsc, osl);
    }
  }
  // ---- phase 2: U2, 59 cols: slices 0-2 get 8, slices 3-7 get 7 ----
  {
    int cb = (slice < 3) ? slice*8 : 24 + (slice-3)*7;
    cb = __builtin_amdgcn_readfirstlane(cb);
    if (slice < 3) {
      float acc[8]; sweep2_run<8>(U2 + cb, xr, acc); fold_run<8>(149 + cb, acc, wsc, osl);
    } else {
      float acc[7]; sweep2_run<7>(U2 + cb, xr, acc); fold_run<7>(149 + cb, acc, wsc, osl);
    }
  }
  // ---- phase 3: U1, 16 cols: 2 per slice ----
  {
    int cb = __builtin_amdgcn_readfirstlane(slice * 2);
    float acc[2] = {0.f, 0.f};
    for (int a0 = 0; a0 < D16; ++a0) {
      float f = xr[a0];
      const float* row = U1 + a0*16 + cb;
      acc[0] = fmaf(row[0], f, acc[0]);
      acc[1] = fmaf(row[1], f, acc[1]);
    }
    fold_run<2>(208 + cb, acc, wsc, osl);
  }

  __syncthreads();

  // ---- reduce 8 slices, write out (coalesced: i fast within lanes) ----
  int c_o = tid >> 3;
  int i0  = (tid & 7) * 2;
  float r0 = 0.f, r1 = 0.f;
  #pragma unroll
  for (int sl = 0; sl < 8; ++sl) {
    const float* p = &osum[(sl*64 + c_o)*17];
    r0 += p[i0]; r1 += p[i0 + 1];
  }
  float2 rv = {r0, r1};
  *(float2*)(out + (size_t)(b*CH + chalf*64 + c_o)*D16 + i0) = rv;
}

// ---------------------------------------------------------------------------
// Host-side: exact reproduction of np.random.default_rng(42) and U_BASIS
// ---------------------------------------------------------------------------
namespace host_rng {

typedef unsigned __int128 u128;

static inline u128 pcg_mult() {
  return (((u128)0x2360ed051fc65da4ULL) << 64) | 0x4385df649fccf645ULL;
}

struct PCG {
  u128 state, inc;
  inline uint64_t next() {
    state = state * pcg_mult() + inc;
    uint64_t hi = (uint64_t)(state >> 64), lo = (uint64_t)state;
    uint64_t x = hi ^ lo;
    unsigned rot = (unsigned)(hi >> 58);
    return (x >> rot) | (x << ((64u - rot) & 63u));
  }
  inline double nextd() { return (double)(next() >> 11) * (1.0 / 9007199254740992.0); }
};

static inline uint32_t hashmix(uint32_t v, uint32_t& hc) {
  v ^= hc; hc *= 0x931e8875u; v *= hc; v ^= v >> 16; return v;
}
static inline uint32_t mixfn(uint32_t x, uint32_t y) {
  uint32_t r = 0xca01f9ddu * x - 0x4973f715u * y; r ^= r >> 16; return r;
}

static void seed42(PCG& g) {
  uint32_t pool[4];
  uint32_t hc = 0x43b0d7e5u;              // INIT_A
  pool[0] = hashmix(42u, hc);
  for (int i = 1; i < 4; ++i) pool[i] = hashmix(0u, hc);
  for (int si = 0; si < 4; ++si)
    for (int di = 0; di < 4; ++di)
      if (si != di) pool[di] = mixfn(pool[di], hashmix(pool[si], hc));
  uint32_t hb = 0x8b51f9ddu;              // INIT_B
  uint32_t w32[8];
  for (int k = 0; k < 8; ++k) {
    uint32_t dv = pool[k & 3];
    dv ^= hb; hb *= 0x58f38dedu; dv *= hb; dv ^= dv >> 16;
    w32[k] = dv;
  }
  uint64_t s0 = (uint64_t)w32[0] | ((uint64_t)w32[1] << 32);
  uint64_t s1 = (uint64_t)w32[2] | ((uint64_t)w32[3] << 32);
  uint64_t s2 = (uint64_t)w32[4] | ((uint64_t)w32[5] << 32);
  uint64_t s3 = (uint64_t)w32[6] | ((uint64_t)w32[7] << 32);
  u128 initstate = ((u128)s0 << 64) | s1;
  u128 initseq   = ((u128)s2 << 64) | s3;
  g.inc   = (initseq << 1) | 1;
  g.state = g.inc;
  g.state += initstate;
  g.state = g.state * pcg_mult() + g.inc;
}

static double zig_w[256], zig_f[256];
static uint64_t zig_k[256];
static const double ZR = 3.6541528853610087963519472518;
static double ZRinv;

static void build_zig() {
  const double m1 = 4503599627370496.0;    // 2^52
  double fr   = std::exp(-0.5 * ZR * ZR);
  double tail = std::sqrt(M_PI * 0.5) * std::erfc(ZR / std::sqrt(2.0));
  double vn   = ZR * fr + tail;
  double q    = vn / fr;
  zig_k[0]   = (uint64_t)((ZR / q) * m1);
  zig_k[1]   = 0;
  zig_w[0]   = q / m1;
  zig_w[255] = ZR / m1;
  zig_f[0]   = 1.0;
  zig_f[255] = fr;
  double tn = ZR, dn = ZR;
  for (int i = 254; i >= 1; --i) {
    dn = std::sqrt(-2.0 * std::log(vn / dn + std::exp(-0.5 * dn * dn)));
    zig_k[i + 1] = (uint64_t)((dn / tn) * m1);
    tn = dn;
    zig_f[i] = std::exp(-0.5 * dn * dn);
    zig_w[i] = dn / m1;
  }
  ZRinv = 1.0 / ZR;
}

static double std_normal(PCG& g) {
  for (;;) {
    uint64_t r = g.next();
    int idx = (int)(r & 0xffu);
    r >>= 8;
    int sign = (int)(r & 1u);
    uint64_t rabs = (r >> 1) & 0x000fffffffffffffULL;
    double x = (double)rabs * zig_w[idx];
    if (sign) x = -x;
    if (rabs < zig_k[idx]) return x;
    if (idx == 0) {
      for (;;) {
        double xx = -ZRinv * std::log1p(-g.nextd());
        double yy = -std::log1p(-g.nextd());
        if (yy + yy > xx * xx)
          return ((rabs >> 8) & 1u) ? -(ZR + xx) : (ZR + xx);
      }
    } else {
      if ((zig_f[idx - 1] - zig_f[idx]) * g.nextd() + zig_f[idx] < std::exp(-0.5 * x * x))
        return x;
    }
  }
}

} // namespace host_rng

static float h_U[U_TOTAL];

static void build_U() {
  using namespace host_rng;
  build_zig();
  PCG g; seed42(g);

  static double S3[U3_FLOATS];
  static double S2[U2_FLOATS];
  static double S1[U1_FLOATS];
  std::memset(S3, 0, sizeof(S3));
  std::memset(S2, 0, sizeof(S2));
  std::memset(S1, 0, sizeof(S1));

  static int tmap[16][16][16];
  static int pmap[16][16];
  { int t = 0;
    for (int a0 = 0; a0 < 16; ++a0)
      for (int a1 = a0; a1 < 16; ++a1)
        for (int a2 = a1; a2 < 16; ++a2) tmap[a0][a1][a2] = t++; }
  { int t = 0;
    for (int a0 = 0; a0 < 16; ++a0)
      for (int a1 = a0; a1 < 16; ++a1) pmap[a0][a1] = t++; }

  const int muls3[4] = {5,8,10,10}, muls2[4] = {2,3,4,4};
  const int dims[4]  = {1,3,5,7};
  const int cb3[4]   = {0,5,29,79};
  const int cb2[4]   = {0,2,11,31};
  const int cb1[4]   = {0,1,4,9};

  static double nrm[16*16*16*10*7];

  for (int ir = 0; ir < 4; ++ir) {
    int mul = muls3[ir], dim = dims[ir];
    long n = 4096L * mul * dim;
    for (long j = 0; j < n; ++j) nrm[j] = std_normal(g);
    long j = 0;
    for (int a0 = 0; a0 < 16; ++a0)
      for (int a1 = 0; a1 < 16; ++a1)
        for (int a2 = 0; a2 < 16; ++a2) {
          int s0 = a0, s1 = a1, s2 = a2, tswap;
          if (s0 > s1) { tswap = s0; s0 = s1; s1 = tswap; }
          if (s1 > s2) { tswap = s1; s1 = s2; s2 = tswap; }
          if (s0 > s1) { tswap = s0; s0 = s1; s1 = tswap; }
          int t = tmap[s0][s1][s2];
          for (int k = 0; k < mul; ++k)
            for (int i = 0; i < dim; ++i, ++j) {
              double u = g.nextd();
              if (u < 0.1) {
                float v = (float)nrm[j];
                v = v / 3.0f;
                S3[t*LD3 + cb3[ir] + k*dim + i] += (double)v;
              }
            }
        }
  }
  for (int ir = 0; ir < 4; ++ir) {
    int mul = muls2[ir], dim = dims[ir];
    long n = 256L * mul * dim;
    for (long j = 0; j < n; ++j) nrm[j] = std_normal(g);
    long j = 0;
    for (int a0 = 0; a0 < 16; ++a0)
      for (int a1 = 0; a1 < 16; ++a1) {
        int s0 = a0 < a1 ? a0 : a1;
        int s1 = a0 < a1 ? a1 : a0;
        int t = pmap[s0][s1];
        for (int k = 0; k < mul; ++k)
          for (int i = 0; i < dim; ++i, ++j) {
            double u = g.nextd();
            if (u < 0.1) {
              float v = (float)nrm[j];
              v = v / 2.0f;
              S2[t*LD2 + cb2[ir] + k*dim + i] += (double)v;
            }
          }
      }
  }
  for (int ir = 0; ir < 4; ++ir) {
    int dim = dims[ir];
    long n = 16L * dim;
    for (long j = 0; j < n; ++j) nrm[j] = std_normal(g);
    long j = 0;
    for (int a0 = 0; a0 < 16; ++a0)
      for (int i = 0; i < dim; ++i, ++j) {
        double u = g.nextd();
        if (u < 0.1) {
          float v = (float)nrm[j];
          S1[a0*16 + cb1[ir] + i] += (double)v;
        }
      }
  }

  for (int i = 0; i < U3_FLOATS; ++i) h_U[i] = (float)S3[i];
  for (int i = 0; i < U2_FLOATS; ++i) h_U[U3_FLOATS + i] = (float)S2[i];
  for (int i = 0; i < U1_FLOATS; ++i) h_U[U3_FLOATS + U2_FLOATS + i] = (float)S1[i];
}

// Build U once at library load; stage into pinned memory so the captured
// H2D memcpy replays at PCIe speed instead of pageable-staging speed.
static float* h_U_pinned = nullptr;
struct UInit {
  UInit() {
    build_U();
    void* p = nullptr;
    if (hipHostMalloc(&p, sizeof(h_U), hipHostMallocDefault) == hipSuccess && p) {
      std::memcpy(p, h_U, sizeof(h_U));
      h_U_pinned = (float*)p;
    }
  }
};
static UInit u_init_once;

// ---------------------------------------------------------------------------
extern "C" void kernel_launch(void* const* d_in, const int* in_sizes, int n_in,
                              void* d_out, int out_size, void* d_ws, size_t ws_size,
                              hipStream_t stream) {
  (void)in_sizes; (void)n_in; (void)d_ws; (void)ws_size; (void)out_size;

  const float* x     = (const float*)d_in[0];
  const int*   index = (const int*)d_in[1];
  const float* embed = (const float*)d_in[2];
  WPtrs wp;
  for (int i = 0; i < 12; ++i) wp.p[i] = (const float*)d_in[3 + i];

  void* uptr = nullptr;
  hipGetSymbolAddress(&uptr, HIP_SYMBOL(g_U));
  const void* src = h_U_pinned ? (const void*)h_U_pinned : (const void*)h_U;
  hipMemcpyAsync(uptr, src, sizeof(h_U), hipMemcpyHostToDevice, stream);

  dim3 gw(NKK, NSP);
  weights_kernel<<<gw, CH, 0, stream>>>(embed, wp);
  dim3 gm(NBATCH, 2);
  main_kernel<<<gm, 512, 0, stream>>>(x, index, (float*)d_out);
}

// Round 3
// 104.145 us; speedup vs baseline: 97.1376x; 97.1376x over previous
//
#include <hip/hip_runtime.h>
#include <cstdint>
#include <cmath>
#include <cstring>

// ---------------------------------------------------------------------------
// Problem constants
// ---------------------------------------------------------------------------
#define D16    16
#define CH     128
#define NBATCH 256
#define NSP    64
#define NRBF   32
#define NKK    50
#define NT3    816
#define NT2    136
#define LD3    160
#define LD2    64
#define U3_FLOATS (NT3*LD3)
#define U2_FLOATS (NT2*LD2)
#define U1_FLOATS 256
#define U_TOTAL   (U3_FLOATS+U2_FLOATS+U1_FLOATS)

#define KPAD   1024          // padded K: 816 triples + 136 pairs + 16 singles + 56 zero
#define NPAD   256           // padded N: 224 real cols + 32 zero
#define NCHUNK 64            // K chunks of 16

typedef __attribute__((ext_vector_type(8)))  short short8;
typedef __attribute__((ext_vector_type(16))) float f32x16;

__device__ uint16_t g_B[NPAD*KPAD];     // bf16 U-as-B matrix, [col][k]
__device__ float    g_ws[NSP*NKK*CH];   // species path weights

__device__ __constant__ int8_t KK_ARR[NKK] = {
  0,0,0,0,0, 1,1,1,1,1,1,1,1, 2,2,2,2,2,2,2,2,2,2, 3,3,3,3,3,3,3,3,3,3,
  4,4, 5,5,5, 6,6,6,6, 7,7,7,7, 8,9,10,11 };
__device__ __constant__ int8_t KK_K[NKK] = {
  0,1,2,3,4, 0,1,2,3,4,5,6,7, 0,1,2,3,4,5,6,7,8,9, 0,1,2,3,4,5,6,7,8,9,
  0,1, 0,1,2, 0,1,2,3, 0,1,2,3, 0,0,0,0 };
__device__ __constant__ int8_t ARR_MUL[12] = {5,8,10,10, 2,3,4,4, 1,1,1,1};

struct WPtrs { const float* p[12]; };

// ---------------------------------------------------------------------------
// Kernel A: ws[s][kk][c] = sum_e embed[s][e]*W[e][k][c]
// ---------------------------------------------------------------------------
__global__ void weights_kernel(const float* __restrict__ embed, WPtrs wp) {
  int kk = blockIdx.x;
  int s  = blockIdx.y;
  int c  = threadIdx.x;
  int ai = KK_ARR[kk];
  int k  = KK_K[kk];
  int mul = ARR_MUL[ai];
  const float* __restrict__ W = wp.p[ai];
  float a = 0.f;
  #pragma unroll 8
  for (int e = 0; e < NRBF; ++e)
    a = fmaf(embed[s*NRBF + e], W[(e*mul + k)*CH + c], a);
  g_ws[(s*NKK + kk)*CH + c] = a;
}

// ---------------------------------------------------------------------------
// Device helpers
// ---------------------------------------------------------------------------
__device__ __forceinline__ uint32_t swz(uint32_t off) {
  // XOR-swizzle: spread 32B-stride rows across banks; bijective, 16B-granular
  return off ^ (((off>>7)&1u)<<4) ^ (((off>>8)&1u)<<5);
}
__device__ __forceinline__ uint16_t f2bf_d(float x) {
  uint32_t u = __float_as_uint(x);
  return (uint16_t)((u + 0x7fffu + ((u>>16)&1u)) >> 16);
}

// t -> packed (a0 | a1<<5 | a2<<10); slot16 = 1.0, slot17 = 0.0 in x rows
__device__ uint32_t unrank_t(int t) {
  if (t < NT3) {
    int acc = 0, a0 = 15;
    for (int a = 0; a < 16; ++a) {
      int n = (16-a)*(17-a)/2;
      if (t < acc + n) { a0 = a; break; }
      acc += n;
    }
    int r = t - acc, a1 = 15;
    for (int a = a0; a < 16; ++a) {
      int m = 16 - a;
      if (r < m) { a1 = a; break; }
      r -= m;
    }
    int a2 = a1 + r;
    return (uint32_t)(a0 | (a1<<5) | (a2<<10));
  }
  if (t < NT3 + NT2) {
    int p = t - NT3, acc = 0, a0 = 15;
    for (int a = 0; a < 16; ++a) {
      int m = 16 - a;
      if (p < acc + m) { a0 = a; break; }
      acc += m;
    }
    int a1 = a0 + (p - acc);
    return (uint32_t)(a0 | (a1<<5) | (16<<10));
  }
  if (t < NT3 + NT2 + 16) {
    int a0 = t - (NT3 + NT2);
    return (uint32_t)(a0 | (16<<5) | (16<<10));
  }
  return (uint32_t)(17 | (17<<5) | (17<<10));   // zero pad
}

// col (0..223) -> (kk<<4)|ii
__device__ uint32_t colpack(int cc) {
  int kk, ii;
  if (cc < 149) {
    if (cc < 5)       { kk = cc;               ii = 0; }
    else if (cc < 29) { int r = cc-5;  kk = 5  + r/3; ii = 1 + r%3; }
    else if (cc < 79) { int r = cc-29; kk = 13 + r/5; ii = 4 + r%5; }
    else              { int r = cc-79; kk = 23 + r/7; ii = 9 + r%7; }
  } else if (cc < 208) {
    int j = cc - 149;
    if (j < 2)        { kk = 33 + j;           ii = 0; }
    else if (j < 11)  { int r = j-2;  kk = 35 + r/3; ii = 1 + r%3; }
    else if (j < 31)  { int r = j-11; kk = 38 + r/5; ii = 4 + r%5; }
    else              { int r = j-31; kk = 42 + r/7; ii = 9 + r%7; }
  } else {
    int j = cc - 208;
    if (j < 1)        { kk = 46; ii = 0; }
    else if (j < 4)   { kk = 47; ii = j; }
    else if (j < 9)   { kk = 48; ii = j; }
    else              { kk = 49; ii = j; }
  }
  return (uint32_t)((kk<<4) | ii);
}

// ---------------------------------------------------------------------------
// Main fused kernel: block = one batch row b (128 channels = GEMM M-tile 128).
// 512 threads = 8 waves: wave w -> (wm = w>>1 in 0..3, wn = w&1), each wave
// computes 32 rows x 128 cols via 4x mfma_f32_32x32x16_bf16 per K16 chunk.
// ---------------------------------------------------------------------------
__global__ __launch_bounds__(512) void main_kernel(const float* __restrict__ x,
                                                   const int* __restrict__ index,
                                                   float* __restrict__ out) {
  __shared__ float    xl[128*18];        // x rows; [16]=1.0, [17]=0.0
  __shared__ float    out_lds[128*18];   // fold accumulator (ii 0..15)
  __shared__ uint32_t tab[KPAD];         // t -> packed triple
  __shared__ uint32_t tab2[NPAD];        // col -> (kk<<4)|ii
  __shared__ uint16_t Abuf[2][128*16];   // feature tile, swizzled
  __shared__ uint16_t Bbuf[2][NPAD*16];  // U tile, swizzled

  const int tid  = threadIdx.x;
  const int lane = tid & 63;
  const int w    = tid >> 6;
  const int wm   = w >> 1;          // 0..3  (M group: rows 32*wm..+32)
  const int wn   = w & 1;           // 0..1  (N group: cols 128*wn..+128)
  const int b    = blockIdx.x;
  const int s    = index[b];

  // ---- stage x rows ----
  { int r = tid >> 2, q = tid & 3;
    float4 v = *(const float4*)(x + ((size_t)b*CH + r)*D16 + q*4);
    float* p = xl + r*18 + q*4;
    p[0]=v.x; p[1]=v.y; p[2]=v.z; p[3]=v.w; }
  if (tid < 128) { xl[tid*18+16] = 1.0f; xl[tid*18+17] = 0.0f; }
  for (int i = tid; i < 128*18; i += 512) out_lds[i] = 0.f;
  tab[tid]       = unrank_t(tid);
  tab[tid + 512] = unrank_t(tid + 512);
  if (tid < NPAD) tab2[tid] = (tid < 224) ? colpack(tid) : 0u;

  // ---- B prefetch setup: thread covers col = tid>>1, k-half = tid&1 ----
  const int bcol = tid >> 1, bhalf = tid & 1;
  const uint16_t* __restrict__ gB = g_B + (size_t)bcol*KPAD + bhalf*8;
  const uint32_t bwoff = swz((uint32_t)(bcol*32 + bhalf*16));

  // feature-gen identity: thread covers row r, k-quad kq
  const int fr = tid & 127, fkq = tid >> 7;
  const float* __restrict__ xr = xl + fr*18;
  const uint32_t fwoff = swz((uint32_t)(fr*32 + fkq*8));

  uint4 bcur = *(const uint4*)(gB);            // chunk 0
  // features chunk 0 -> Abuf[0]
  {
    int t0 = fkq*4;
    uint32_t v0 = unrank_t(t0+0), v1 = unrank_t(t0+1), v2 = unrank_t(t0+2), v3 = unrank_t(t0+3);
    // (tab not yet synced; unrank directly for chunk 0 — xl write above is ours? No:
    // xr spans other threads' rows. Need a barrier before using xl.)
    // -> handled below: we sync first, then generate chunk 0.
    (void)v0;(void)v1;(void)v2;(void)v3;
  }
  __syncthreads();   // xl, tab, tab2, out_lds ready

  // generate chunk 0 features + store B chunk 0
  {
    int t0 = fkq*4;
    uint16_t h[4];
    #pragma unroll
    for (int j = 0; j < 4; ++j) {
      uint32_t v = tab[t0 + j];
      h[j] = f2bf_d(xr[v&31] * xr[(v>>5)&31] * xr[(v>>10)&31]);
    }
    uint2 pk; pk.x = (uint32_t)h[0] | ((uint32_t)h[1]<<16);
    pk.y = (uint32_t)h[2] | ((uint32_t)h[3]<<16);
    *(uint2*)((char*)Abuf[0] + fwoff) = pk;
    *(uint4*)((char*)Bbuf[0] + bwoff) = bcur;
  }
  bcur = *(const uint4*)(gB + 1*16);           // chunk 1
  __syncthreads();

  f32x16 acc[4];
  #pragma unroll
  for (int nt = 0; nt < 4; ++nt)
    #pragma unroll
    for (int q = 0; q < 16; ++q) acc[nt][q] = 0.f;

  const int arow   = wm*32 + (lane & 31);
  const int kg     = lane >> 5;
  const uint32_t aroff = swz((uint32_t)(arow*32 + kg*16));
  uint32_t broff[4];
  #pragma unroll
  for (int nt = 0; nt < 4; ++nt) {
    int col = wn*128 + nt*32 + (lane & 31);
    broff[nt] = swz((uint32_t)(col*32 + kg*16));
  }

  for (int c = 0; c < NCHUNK; ++c) {
    const int cb = c & 1, nb = cb ^ 1;
    if (c < NCHUNK-1) {
      // features for chunk c+1
      int t0 = (c+1)*16 + fkq*4;
      uint16_t h[4];
      #pragma unroll
      for (int j = 0; j < 4; ++j) {
        uint32_t v = tab[t0 + j];
        h[j] = f2bf_d(xr[v&31] * xr[(v>>5)&31] * xr[(v>>10)&31]);
      }
      uint2 pk; pk.x = (uint32_t)h[0] | ((uint32_t)h[1]<<16);
      pk.y = (uint32_t)h[2] | ((uint32_t)h[3]<<16);
      *(uint2*)((char*)Abuf[nb] + fwoff) = pk;
      // stage B chunk c+1 (loaded one iteration ago)
      *(uint4*)((char*)Bbuf[nb] + bwoff) = bcur;
      if (c < NCHUNK-2) bcur = *(const uint4*)(gB + (c+2)*16);
    }
    // fragments + MFMA on chunk c
    short8 af = *(const short8*)((const char*)Abuf[cb] + aroff);
    #pragma unroll
    for (int nt = 0; nt < 4; ++nt) {
      short8 bf = *(const short8*)((const char*)Bbuf[cb] + broff[nt]);
      acc[nt] = __builtin_amdgcn_mfma_f32_32x32x16_bf16(af, bf, acc[nt], 0, 0, 0);
    }
    __syncthreads();
  }

  // ---- epilogue: fold with ws into out_lds via LDS atomics ----
  #pragma unroll
  for (int nt = 0; nt < 4; ++nt) {
    int col = wn*128 + nt*32 + (lane & 31);
    if (col < 224) {
      uint32_t v = tab2[col];
      int kk = v >> 4, ii = v & 15;
      const float* wsrow = g_ws + ((size_t)s*NKK + kk)*CH + wm*32;
      #pragma unroll
      for (int qg = 0; qg < 4; ++qg) {
        int rlb = 8*qg + 4*(lane>>5);
        float4 wv = *(const float4*)(wsrow + rlb);
        atomicAdd(&out_lds[(wm*32 + rlb + 0)*18 + ii], wv.x * acc[nt][qg*4+0]);
        atomicAdd(&out_lds[(wm*32 + rlb + 1)*18 + ii], wv.y * acc[nt][qg*4+1]);
        atomicAdd(&out_lds[(wm*32 + rlb + 2)*18 + ii], wv.z * acc[nt][qg*4+2]);
        atomicAdd(&out_lds[(wm*32 + rlb + 3)*18 + ii], wv.w * acc[nt][qg*4+3]);
      }
    }
  }
  __syncthreads();

  // ---- write out: coalesced float4 ----
  { int cch = tid >> 2, q = tid & 3;
    float4 o;
    o.x = out_lds[cch*18 + q*4 + 0];
    o.y = out_lds[cch*18 + q*4 + 1];
    o.z = out_lds[cch*18 + q*4 + 2];
    o.w = out_lds[cch*18 + q*4 + 3];
    *(float4*)(out + ((size_t)b*CH + cch)*D16 + q*4) = o; }
}

// ---------------------------------------------------------------------------
// Host-side: exact reproduction of np.random.default_rng(42) and U_BASIS
// ---------------------------------------------------------------------------
namespace host_rng {

typedef unsigned __int128 u128;

static inline u128 pcg_mult() {
  return (((u128)0x2360ed051fc65da4ULL) << 64) | 0x4385df649fccf645ULL;
}

struct PCG {
  u128 state, inc;
  inline uint64_t next() {
    state = state * pcg_mult() + inc;
    uint64_t hi = (uint64_t)(state >> 64), lo = (uint64_t)state;
    uint64_t x = hi ^ lo;
    unsigned rot = (unsigned)(hi >> 58);
    return (x >> rot) | (x << ((64u - rot) & 63u));
  }
  inline double nextd() { return (double)(next() >> 11) * (1.0 / 9007199254740992.0); }
};

static inline uint32_t hashmix(uint32_t v, uint32_t& hc) {
  v ^= hc; hc *= 0x931e8875u; v *= hc; v ^= v >> 16; return v;
}
static inline uint32_t mixfn(uint32_t x, uint32_t y) {
  uint32_t r = 0xca01f9ddu * x - 0x4973f715u * y; r ^= r >> 16; return r;
}

static void seed42(PCG& g) {
  uint32_t pool[4];
  uint32_t hc = 0x43b0d7e5u;              // INIT_A
  pool[0] = hashmix(42u, hc);
  for (int i = 1; i < 4; ++i) pool[i] = hashmix(0u, hc);
  for (int si = 0; si < 4; ++si)
    for (int di = 0; di < 4; ++di)
      if (si != di) pool[di] = mixfn(pool[di], hashmix(pool[si], hc));
  uint32_t hb = 0x8b51f9ddu;              // INIT_B
  uint32_t w32[8];
  for (int k = 0; k < 8; ++k) {
    uint32_t dv = pool[k & 3];
    dv ^= hb; hb *= 0x58f38dedu; dv *= hb; dv ^= dv >> 16;
    w32[k] = dv;
  }
  uint64_t s0 = (uint64_t)w32[0] | ((uint64_t)w32[1] << 32);
  uint64_t s1 = (uint64_t)w32[2] | ((uint64_t)w32[3] << 32);
  uint64_t s2 = (uint64_t)w32[4] | ((uint64_t)w32[5] << 32);
  uint64_t s3 = (uint64_t)w32[6] | ((uint64_t)w32[7] << 32);
  u128 initstate = ((u128)s0 << 64) | s1;
  u128 initseq   = ((u128)s2 << 64) | s3;
  g.inc   = (initseq << 1) | 1;
  g.state = g.inc;
  g.state += initstate;
  g.state = g.state * pcg_mult() + g.inc;
}

static double zig_w[256], zig_f[256];
static uint64_t zig_k[256];
static const double ZR = 3.6541528853610087963519472518;
static double ZRinv;

static void build_zig() {
  const double m1 = 4503599627370496.0;    // 2^52
  double fr   = std::exp(-0.5 * ZR * ZR);
  double tail = std::sqrt(M_PI * 0.5) * std::erfc(ZR / std::sqrt(2.0));
  double vn   = ZR * fr + tail;
  double q    = vn / fr;
  zig_k[0]   = (uint64_t)((ZR / q) * m1);
  zig_k[1]   = 0;
  zig_w[0]   = q / m1;
  zig_w[255] = ZR / m1;
  zig_f[0]   = 1.0;
  zig_f[255] = fr;
  double tn = ZR, dn = ZR;
  for (int i = 254; i >= 1; --i) {
    dn = std::sqrt(-2.0 * std::log(vn / dn + std::exp(-0.5 * dn * dn)));
    zig_k[i + 1] = (uint64_t)((dn / tn) * m1);
    tn = dn;
    zig_f[i] = std::exp(-0.5 * dn * dn);
    zig_w[i] = dn / m1;
  }
  ZRinv = 1.0 / ZR;
}

static double std_normal(PCG& g) {
  for (;;) {
    uint64_t r = g.next();
    int idx = (int)(r & 0xffu);
    r >>= 8;
    int sign = (int)(r & 1u);
    uint64_t rabs = (r >> 1) & 0x000fffffffffffffULL;
    double x = (double)rabs * zig_w[idx];
    if (sign) x = -x;
    if (rabs < zig_k[idx]) return x;
    if (idx == 0) {
      for (;;) {
        double xx = -ZRinv * std::log1p(-g.nextd());
        double yy = -std::log1p(-g.nextd());
        if (yy + yy > xx * xx)
          return ((rabs >> 8) & 1u) ? -(ZR + xx) : (ZR + xx);
      }
    } else {
      if ((zig_f[idx - 1] - zig_f[idx]) * g.nextd() + zig_f[idx] < std::exp(-0.5 * x * x))
        return x;
    }
  }
}

} // namespace host_rng

static float h_U[U_TOTAL];

static void build_U() {
  using namespace host_rng;
  build_zig();
  PCG g; seed42(g);

  static double S3[U3_FLOATS];
  static double S2[U2_FLOATS];
  static double S1[U1_FLOATS];
  std::memset(S3, 0, sizeof(S3));
  std::memset(S2, 0, sizeof(S2));
  std::memset(S1, 0, sizeof(S1));

  static int tmap[16][16][16];
  static int pmap[16][16];
  { int t = 0;
    for (int a0 = 0; a0 < 16; ++a0)
      for (int a1 = a0; a1 < 16; ++a1)
        for (int a2 = a1; a2 < 16; ++a2) tmap[a0][a1][a2] = t++; }
  { int t = 0;
    for (int a0 = 0; a0 < 16; ++a0)
      for (int a1 = a0; a1 < 16; ++a1) pmap[a0][a1] = t++; }

  const int muls3[4] = {5,8,10,10}, muls2[4] = {2,3,4,4};
  const int dims[4]  = {1,3,5,7};
  const int cb3[4]   = {0,5,29,79};
  const int cb2[4]   = {0,2,11,31};
  const int cb1[4]   = {0,1,4,9};

  static double nrm[16*16*16*10*7];

  for (int ir = 0; ir < 4; ++ir) {
    int mul = muls3[ir], dim = dims[ir];
    long n = 4096L * mul * dim;
    for (long j = 0; j < n; ++j) nrm[j] = std_normal(g);
    long j = 0;
    for (int a0 = 0; a0 < 16; ++a0)
      for (int a1 = 0; a1 < 16; ++a1)
        for (int a2 = 0; a2 < 16; ++a2) {
          int s0 = a0, s1 = a1, s2 = a2, tswap;
          if (s0 > s1) { tswap = s0; s0 = s1; s1 = tswap; }
          if (s1 > s2) { tswap = s1; s1 = s2; s2 = tswap; }
          if (s0 > s1) { tswap = s0; s0 = s1; s1 = tswap; }
          int t = tmap[s0][s1][s2];
          for (int k = 0; k < mul; ++k)
            for (int i = 0; i < dim; ++i, ++j) {
              double u = g.nextd();
              if (u < 0.1) {
                float v = (float)nrm[j];
                v = v / 3.0f;
                S3[t*LD3 + cb3[ir] + k*dim + i] += (double)v;
              }
            }
        }
  }
  for (int ir = 0; ir < 4; ++ir) {
    int mul = muls2[ir], dim = dims[ir];
    long n = 256L * mul * dim;
    for (long j = 0; j < n; ++j) nrm[j] = std_normal(g);
    long j = 0;
    for (int a0 = 0; a0 < 16; ++a0)
      for (int a1 = 0; a1 < 16; ++a1) {
        int s0 = a0 < a1 ? a0 : a1;
        int s1 = a0 < a1 ? a1 : a0;
        int t = pmap[s0][s1];
        for (int k = 0; k < mul; ++k)
          for (int i = 0; i < dim; ++i, ++j) {
            double u = g.nextd();
            if (u < 0.1) {
              float v = (float)nrm[j];
              v = v / 2.0f;
              S2[t*LD2 + cb2[ir] + k*dim + i] += (double)v;
            }
          }
      }
  }
  for (int ir = 0; ir < 4; ++ir) {
    int dim = dims[ir];
    long n = 16L * dim;
    for (long j = 0; j < n; ++j) nrm[j] = std_normal(g);
    long j = 0;
    for (int a0 = 0; a0 < 16; ++a0)
      for (int i = 0; i < dim; ++i, ++j) {
        double u = g.nextd();
        if (u < 0.1) {
          float v = (float)nrm[j];
          S1[a0*16 + cb1[ir] + i] += (double)v;
        }
      }
  }

  for (int i = 0; i < U3_FLOATS; ++i) h_U[i] = (float)S3[i];
  for (int i = 0; i < U2_FLOATS; ++i) h_U[U3_FLOATS + i] = (float)S2[i];
  for (int i = 0; i < U1_FLOATS; ++i) h_U[U3_FLOATS + U2_FLOATS + i] = (float)S1[i];
}

// ---------------------------------------------------------------------------
// Build bf16 B matrix [col][k] from U tables; pin it for fast captured H2D.
// ---------------------------------------------------------------------------
static uint16_t h_B_arr[NPAD*KPAD];
static const uint16_t* h_B_src = h_B_arr;

static inline uint16_t f2bf_h(float x) {
  uint32_t u; std::memcpy(&u, &x, 4);
  return (uint16_t)((u + 0x7fffu + ((u>>16)&1u)) >> 16);
}

struct UInit {
  UInit() {
    build_U();
    for (int col = 0; col < NPAD; ++col)
      for (int k = 0; k < KPAD; ++k) {
        float v = 0.f;
        if (col < 149)       { if (k < NT3) v = h_U[k*LD3 + col]; }
        else if (col < 208)  { if (k >= NT3 && k < NT3+NT2) v = h_U[U3_FLOATS + (k-NT3)*LD2 + (col-149)]; }
        else if (col < 224)  { if (k >= NT3+NT2 && k < NT3+NT2+16) v = h_U[U3_FLOATS+U2_FLOATS + (k-(NT3+NT2))*16 + (col-208)]; }
        h_B_arr[col*KPAD + k] = f2bf_h(v);
      }
    void* p = nullptr;
    if (hipHostMalloc(&p, sizeof(h_B_arr), hipHostMallocDefault) == hipSuccess && p) {
      std::memcpy(p, h_B_arr, sizeof(h_B_arr));
      h_B_src = (const uint16_t*)p;
    }
  }
};
static UInit u_init_once;

// ---------------------------------------------------------------------------
extern "C" void kernel_launch(void* const* d_in, const int* in_sizes, int n_in,
                              void* d_out, int out_size, void* d_ws, size_t ws_size,
                              hipStream_t stream) {
  (void)in_sizes; (void)n_in; (void)d_ws; (void)ws_size; (void)out_size;

  const float* x     = (const float*)d_in[0];
  const int*   index = (const int*)d_in[1];
  const float* embed = (const float*)d_in[2];
  WPtrs wp;
  for (int i = 0; i < 12; ++i) wp.p[i] = (const float*)d_in[3 + i];

  void* bptr = nullptr;
  hipGetSymbolAddress(&bptr, HIP_SYMBOL(g_B));
  hipMemcpyAsync(bptr, h_B_src, sizeof(h_B_arr), hipMemcpyHostToDevice, stream);

  dim3 gw(NKK, NSP);
  weights_kernel<<<gw, CH, 0, stream>>>(embed, wp);
  main_kernel<<<NBATCH, 512, 0, stream>>>(x, index, (float*)d_out);
}

// Round 4
// 81.561 us; speedup vs baseline: 124.0344x; 1.2769x over previous
//
#include <hip/hip_runtime.h>
#include <cstdint>
#include <cmath>
#include <cstring>

// ---------------------------------------------------------------------------
// Problem constants
// ---------------------------------------------------------------------------
#define D16    16
#define CH     128
#define NBATCH 256
#define NSP    64
#define NRBF   32
#define NKK    50
#define NT3    816
#define NT2    136
#define LD3    160
#define LD2    64
#define U3_FLOATS (NT3*LD3)
#define U2_FLOATS (NT2*LD2)
#define U1_FLOATS 256
#define U_TOTAL   (U3_FLOATS+U2_FLOATS+U1_FLOATS)

#define KPAD   1024
#define NPAD   256

typedef __attribute__((ext_vector_type(8)))  short short8;
typedef __attribute__((ext_vector_type(16))) float f32x16;

__device__ uint16_t g_B[NPAD*KPAD];     // bf16 U-as-B, chunk-major: [c][khalf][col][8]
__device__ float    g_ws[NSP*NKK*CH];

__device__ __constant__ int8_t KK_ARR[NKK] = {
  0,0,0,0,0, 1,1,1,1,1,1,1,1, 2,2,2,2,2,2,2,2,2,2, 3,3,3,3,3,3,3,3,3,3,
  4,4, 5,5,5, 6,6,6,6, 7,7,7,7, 8,9,10,11 };
__device__ __constant__ int8_t KK_K[NKK] = {
  0,1,2,3,4, 0,1,2,3,4,5,6,7, 0,1,2,3,4,5,6,7,8,9, 0,1,2,3,4,5,6,7,8,9,
  0,1, 0,1,2, 0,1,2,3, 0,1,2,3, 0,0,0,0 };
__device__ __constant__ int8_t ARR_MUL[12] = {5,8,10,10, 2,3,4,4, 1,1,1,1};

struct WPtrs { const float* p[12]; };

// ---------------------------------------------------------------------------
// Compile-time monomial table: k -> (a0,a1,a2); 16 = "absent", 17 = zero pad
// Enumeration MUST match host B build: triples lex (a0<=a1<=a2), pairs, singles.
// ---------------------------------------------------------------------------
struct TTab { uint8_t a0[KPAD]; uint8_t a1[KPAD]; uint8_t a2[KPAD]; };
constexpr TTab make_tab() {
  TTab t{};
  int i = 0;
  for (int A = 0; A < 16; ++A)
    for (int B = A; B < 16; ++B)
      for (int C = B; C < 16; ++C) { t.a0[i]=(uint8_t)A; t.a1[i]=(uint8_t)B; t.a2[i]=(uint8_t)C; ++i; }
  for (int A = 0; A < 16; ++A)
    for (int B = A; B < 16; ++B) { t.a0[i]=(uint8_t)A; t.a1[i]=(uint8_t)B; t.a2[i]=16; ++i; }
  for (int A = 0; A < 16; ++A) { t.a0[i]=(uint8_t)A; t.a1[i]=16; t.a2[i]=16; ++i; }
  for (; i < KPAD; ++i) { t.a0[i]=17; t.a1[i]=17; t.a2[i]=17; }
  return t;
}
static constexpr TTab TT = make_tab();

template<int K>
__device__ __forceinline__ float featK(const float (&xv)[16]) {
  constexpr int A = TT.a0[K], B = TT.a1[K], C = TT.a2[K];
  if constexpr (A == 17) { return 0.f; }
  else {
    float m = xv[A];
    if constexpr (B < 16) m *= xv[B];
    if constexpr (C < 16) m *= xv[C];
    return m;
  }
}

template<int K0>
__device__ __forceinline__ uint32_t pack2(const float (&xv)[16]) {
  if constexpr (TT.a0[K0] == 17 && TT.a0[K0+1] == 17) { return 0u; }
  else {
    float lo = featK<K0>(xv);
    float hi = featK<K0+1>(xv);
    uint32_t d;
    asm("v_cvt_pk_bf16_f32 %0, %1, %2" : "=v"(d) : "v"(lo), "v"(hi));
    return d;
  }
}

template<int CHUNK>
__device__ __forceinline__ short8 build_frag(const float (&xv)[16], bool kg_hi) {
  uint32_t pk0 = pack2<CHUNK*16 + 0>(xv);
  uint32_t pk1 = pack2<CHUNK*16 + 2>(xv);
  uint32_t pk2 = pack2<CHUNK*16 + 4>(xv);
  uint32_t pk3 = pack2<CHUNK*16 + 6>(xv);
  uint32_t pk4 = pack2<CHUNK*16 + 8>(xv);
  uint32_t pk5 = pack2<CHUNK*16 + 10>(xv);
  uint32_t pk6 = pack2<CHUNK*16 + 12>(xv);
  uint32_t pk7 = pack2<CHUNK*16 + 14>(xv);
  union { uint32_t u[4]; short8 s; } r;
  r.u[0] = kg_hi ? pk4 : pk0;
  r.u[1] = kg_hi ? pk5 : pk1;
  r.u[2] = kg_hi ? pk6 : pk2;
  r.u[3] = kg_hi ? pk7 : pk3;
  return r.s;
}

// col (0..223) -> (kk<<4)|ii
__device__ uint32_t colpack(int cc) {
  int kk, ii;
  if (cc < 149) {
    if (cc < 5)       { kk = cc;               ii = 0; }
    else if (cc < 29) { int r = cc-5;  kk = 5  + r/3; ii = 1 + r%3; }
    else if (cc < 79) { int r = cc-29; kk = 13 + r/5; ii = 4 + r%5; }
    else              { int r = cc-79; kk = 23 + r/7; ii = 9 + r%7; }
  } else if (cc < 208) {
    int j = cc - 149;
    if (j < 2)        { kk = 33 + j;           ii = 0; }
    else if (j < 11)  { int r = j-2;  kk = 35 + r/3; ii = 1 + r%3; }
    else if (j < 31)  { int r = j-11; kk = 38 + r/5; ii = 4 + r%5; }
    else              { int r = j-31; kk = 42 + r/7; ii = 9 + r%7; }
  } else {
    int j = cc - 208;
    if (j < 1)        { kk = 46; ii = 0; }
    else if (j < 4)   { kk = 47; ii = j; }
    else if (j < 9)   { kk = 48; ii = j; }
    else              { kk = 49; ii = j; }
  }
  return (uint32_t)((kk<<4) | ii);
}

// ---------------------------------------------------------------------------
// Kernel A: ws[s][kk][c]
// ---------------------------------------------------------------------------
__global__ void weights_kernel(const float* __restrict__ embed, WPtrs wp) {
  int kk = blockIdx.x;
  int s  = blockIdx.y;
  int c  = threadIdx.x;
  int ai = KK_ARR[kk];
  int k  = KK_K[kk];
  int mul = ARR_MUL[ai];
  const float* __restrict__ W = wp.p[ai];
  float a = 0.f;
  #pragma unroll 8
  for (int e = 0; e < NRBF; ++e)
    a = fmaf(embed[s*NRBF + e], W[(e*mul + k)*CH + c], a);
  g_ws[(s*NKK + kk)*CH + c] = a;
}

// ---------------------------------------------------------------------------
// Main kernel: block = one b. 512 thr = 8 waves: wm=w>>1 (rows), wn=w&1 (cols).
// A-fragments built in registers (compile-time monomials); B staged in LDS,
// K_STEP=64 (4 chunks) double-buffered, 16 barriers total.
// ---------------------------------------------------------------------------
__global__ __launch_bounds__(512) void main_kernel(const float* __restrict__ x,
                                                   const int* __restrict__ index,
                                                   float* __restrict__ out) {
  __shared__ uint16_t Bbuf[2][4][2][256][8];   // [buf][q][kg][col][8k] = 64 KB
  __shared__ float    out_lds[128*18];
  __shared__ uint32_t tab2[256];

  const int tid  = threadIdx.x;
  const int lane = tid & 63;
  const int l31  = lane & 31;
  const int kg   = lane >> 5;
  const bool kg_hi = (kg != 0);
  const int w    = tid >> 6;
  const int wm   = w >> 1;          // 0..3
  const int wn   = w & 1;           // 0..1
  const int b    = blockIdx.x;
  const int s    = index[b];

  // ---- x row into registers ----
  const int row = wm*32 + l31;
  float xv[16];
  {
    const float4* xs = (const float4*)(x + ((size_t)b*CH + row)*D16);
    #pragma unroll
    for (int qq = 0; qq < 4; ++qq) {
      float4 v = xs[qq];
      xv[qq*4+0]=v.x; xv[qq*4+1]=v.y; xv[qq*4+2]=v.z; xv[qq*4+3]=v.w;
    }
  }

  for (int i = tid; i < 128*18; i += 512) out_lds[i] = 0.f;
  if (tid < 256) tab2[tid] = (tid < 224) ? colpack(tid) : 0u;

  // ---- stage 0 B into buf0 ----
  #pragma unroll
  for (int q = 0; q < 4; ++q) {
    uint4 v = *(const uint4*)(g_B + ((size_t)q*512 + tid)*8);
    *(uint4*)((char*)&Bbuf[0][q][0][0][0] + tid*16) = v;
  }
  __syncthreads();

  f32x16 acc[4];
  #pragma unroll
  for (int nt = 0; nt < 4; ++nt)
    #pragma unroll
    for (int q = 0; q < 16; ++q) acc[nt][q] = 0.f;

  uint4 bpre[4];

#define DO_CHUNK(CC, CB) { \
    short8 af = build_frag<(CC)>(xv, kg_hi); \
    _Pragma("unroll") \
    for (int nt = 0; nt < 4; ++nt) { \
      short8 bf = *(const short8*)&Bbuf[(CB)][(CC)&3][kg][wn*128 + nt*32 + l31][0]; \
      acc[nt] = __builtin_amdgcn_mfma_f32_32x32x16_bf16(af, bf, acc[nt], 0, 0, 0); \
    } }

#define DO_STAGE(S) { \
    if ((S) < 15) { \
      _Pragma("unroll") \
      for (int q = 0; q < 4; ++q) \
        bpre[q] = *(const uint4*)(g_B + ((size_t)(((S)+1)*4+q)*512 + tid)*8); \
    } \
    DO_CHUNK((S)*4+0, (S)&1) \
    DO_CHUNK((S)*4+1, (S)&1) \
    DO_CHUNK((S)*4+2, (S)&1) \
    DO_CHUNK((S)*4+3, (S)&1) \
    if ((S) < 15) { \
      _Pragma("unroll") \
      for (int q = 0; q < 4; ++q) \
        *(uint4*)((char*)&Bbuf[((S)+1)&1][q][0][0][0] + tid*16) = bpre[q]; \
    } \
    __syncthreads(); }

  DO_STAGE(0)  DO_STAGE(1)  DO_STAGE(2)  DO_STAGE(3)
  DO_STAGE(4)  DO_STAGE(5)  DO_STAGE(6)  DO_STAGE(7)
  DO_STAGE(8)  DO_STAGE(9)  DO_STAGE(10) DO_STAGE(11)
  DO_STAGE(12) DO_STAGE(13) DO_STAGE(14) DO_STAGE(15)

#undef DO_STAGE
#undef DO_CHUNK

  // ---- epilogue: fold with ws into out_lds ----
  #pragma unroll
  for (int nt = 0; nt < 4; ++nt) {
    int col = wn*128 + nt*32 + l31;
    if (col < 224) {
      uint32_t v = tab2[col];
      int kk = v >> 4, ii = v & 15;
      const float* wsrow = g_ws + ((size_t)s*NKK + kk)*CH + wm*32;
      #pragma unroll
      for (int qg = 0; qg < 4; ++qg) {
        int rlb = 8*qg + 4*kg;
        float4 wv = *(const float4*)(wsrow + rlb);
        atomicAdd(&out_lds[(wm*32 + rlb + 0)*18 + ii], wv.x * acc[nt][qg*4+0]);
        atomicAdd(&out_lds[(wm*32 + rlb + 1)*18 + ii], wv.y * acc[nt][qg*4+1]);
        atomicAdd(&out_lds[(wm*32 + rlb + 2)*18 + ii], wv.z * acc[nt][qg*4+2]);
        atomicAdd(&out_lds[(wm*32 + rlb + 3)*18 + ii], wv.w * acc[nt][qg*4+3]);
      }
    }
  }
  __syncthreads();

  // ---- write out ----
  { int cch = tid >> 2, q = tid & 3;
    float4 o;
    o.x = out_lds[cch*18 + q*4 + 0];
    o.y = out_lds[cch*18 + q*4 + 1];
    o.z = out_lds[cch*18 + q*4 + 2];
    o.w = out_lds[cch*18 + q*4 + 3];
    *(float4*)(out + ((size_t)b*CH + cch)*D16 + q*4) = o; }
}

// ---------------------------------------------------------------------------
// Host-side: exact reproduction of np.random.default_rng(42) and U_BASIS
// ---------------------------------------------------------------------------
namespace host_rng {

typedef unsigned __int128 u128;

static inline u128 pcg_mult() {
  return (((u128)0x2360ed051fc65da4ULL) << 64) | 0x4385df649fccf645ULL;
}

struct PCG {
  u128 state, inc;
  inline uint64_t next() {
    state = state * pcg_mult() + inc;
    uint64_t hi = (uint64_t)(state >> 64), lo = (uint64_t)state;
    uint64_t x = hi ^ lo;
    unsigned rot = (unsigned)(hi >> 58);
    return (x >> rot) | (x << ((64u - rot) & 63u));
  }
  inline double nextd() { return (double)(next() >> 11) * (1.0 / 9007199254740992.0); }
};

static inline uint32_t hashmix(uint32_t v, uint32_t& hc) {
  v ^= hc; hc *= 0x931e8875u; v *= hc; v ^= v >> 16; return v;
}
static inline uint32_t mixfn(uint32_t x, uint32_t y) {
  uint32_t r = 0xca01f9ddu * x - 0x4973f715u * y; r ^= r >> 16; return r;
}

static void seed42(PCG& g) {
  uint32_t pool[4];
  uint32_t hc = 0x43b0d7e5u;              // INIT_A
  pool[0] = hashmix(42u, hc);
  for (int i = 1; i < 4; ++i) pool[i] = hashmix(0u, hc);
  for (int si = 0; si < 4; ++si)
    for (int di = 0; di < 4; ++di)
      if (si != di) pool[di] = mixfn(pool[di], hashmix(pool[si], hc));
  uint32_t hb = 0x8b51f9ddu;              // INIT_B
  uint32_t w32[8];
  for (int k = 0; k < 8; ++k) {
    uint32_t dv = pool[k & 3];
    dv ^= hb; hb *= 0x58f38dedu; dv *= hb; dv ^= dv >> 16;
    w32[k] = dv;
  }
  uint64_t s0 = (uint64_t)w32[0] | ((uint64_t)w32[1] << 32);
  uint64_t s1 = (uint64_t)w32[2] | ((uint64_t)w32[3] << 32);
  uint64_t s2 = (uint64_t)w32[4] | ((uint64_t)w32[5] << 32);
  uint64_t s3 = (uint64_t)w32[6] | ((uint64_t)w32[7] << 32);
  u128 initstate = ((u128)s0 << 64) | s1;
  u128 initseq   = ((u128)s2 << 64) | s3;
  g.inc   = (initseq << 1) | 1;
  g.state = g.inc;
  g.state += initstate;
  g.state = g.state * pcg_mult() + g.inc;
}

static double zig_w[256], zig_f[256];
static uint64_t zig_k[256];
static const double ZR = 3.6541528853610087963519472518;
static double ZRinv;

static void build_zig() {
  const double m1 = 4503599627370496.0;    // 2^52
  double fr   = std::exp(-0.5 * ZR * ZR);
  double tail = std::sqrt(M_PI * 0.5) * std::erfc(ZR / std::sqrt(2.0));
  double vn   = ZR * fr + tail;
  double q    = vn / fr;
  zig_k[0]   = (uint64_t)((ZR / q) * m1);
  zig_k[1]   = 0;
  zig_w[0]   = q / m1;
  zig_w[255] = ZR / m1;
  zig_f[0]   = 1.0;
  zig_f[255] = fr;
  double tn = ZR, dn = ZR;
  for (int i = 254; i >= 1; --i) {
    dn = std::sqrt(-2.0 * std::log(vn / dn + std::exp(-0.5 * dn * dn)));
    zig_k[i + 1] = (uint64_t)((dn / tn) * m1);
    tn = dn;
    zig_f[i] = std::exp(-0.5 * dn * dn);
    zig_w[i] = dn / m1;
  }
  ZRinv = 1.0 / ZR;
}

static double std_normal(PCG& g) {
  for (;;) {
    uint64_t r = g.next();
    int idx = (int)(r & 0xffu);
    r >>= 8;
    int sign = (int)(r & 1u);
    uint64_t rabs = (r >> 1) & 0x000fffffffffffffULL;
    double x = (double)rabs * zig_w[idx];
    if (sign) x = -x;
    if (rabs < zig_k[idx]) return x;
    if (idx == 0) {
      for (;;) {
        double xx = -ZRinv * std::log1p(-g.nextd());
        double yy = -std::log1p(-g.nextd());
        if (yy + yy > xx * xx)
          return ((rabs >> 8) & 1u) ? -(ZR + xx) : (ZR + xx);
      }
    } else {
      if ((zig_f[idx - 1] - zig_f[idx]) * g.nextd() + zig_f[idx] < std::exp(-0.5 * x * x))
        return x;
    }
  }
}

} // namespace host_rng

static float h_U[U_TOTAL];

static void build_U() {
  using namespace host_rng;
  build_zig();
  PCG g; seed42(g);

  static double S3[U3_FLOATS];
  static double S2[U2_FLOATS];
  static double S1[U1_FLOATS];
  std::memset(S3, 0, sizeof(S3));
  std::memset(S2, 0, sizeof(S2));
  std::memset(S1, 0, sizeof(S1));

  static int tmap[16][16][16];
  static int pmap[16][16];
  { int t = 0;
    for (int a0 = 0; a0 < 16; ++a0)
      for (int a1 = a0; a1 < 16; ++a1)
        for (int a2 = a1; a2 < 16; ++a2) tmap[a0][a1][a2] = t++; }
  { int t = 0;
    for (int a0 = 0; a0 < 16; ++a0)
      for (int a1 = a0; a1 < 16; ++a1) pmap[a0][a1] = t++; }

  const int muls3[4] = {5,8,10,10}, muls2[4] = {2,3,4,4};
  const int dims[4]  = {1,3,5,7};
  const int cb3[4]   = {0,5,29,79};
  const int cb2[4]   = {0,2,11,31};
  const int cb1[4]   = {0,1,4,9};

  static double nrm[16*16*16*10*7];

  for (int ir = 0; ir < 4; ++ir) {
    int mul = muls3[ir], dim = dims[ir];
    long n = 4096L * mul * dim;
    for (long j = 0; j < n; ++j) nrm[j] = std_normal(g);
    long j = 0;
    for (int a0 = 0; a0 < 16; ++a0)
      for (int a1 = 0; a1 < 16; ++a1)
        for (int a2 = 0; a2 < 16; ++a2) {
          int s0 = a0, s1 = a1, s2 = a2, tswap;
          if (s0 > s1) { tswap = s0; s0 = s1; s1 = tswap; }
          if (s1 > s2) { tswap = s1; s1 = s2; s2 = tswap; }
          if (s0 > s1) { tswap = s0; s0 = s1; s1 = tswap; }
          int t = tmap[s0][s1][s2];
          for (int k = 0; k < mul; ++k)
            for (int i = 0; i < dim; ++i, ++j) {
              double u = g.nextd();
              if (u < 0.1) {
                float v = (float)nrm[j];
                v = v / 3.0f;
                S3[t*LD3 + cb3[ir] + k*dim + i] += (double)v;
              }
            }
        }
  }
  for (int ir = 0; ir < 4; ++ir) {
    int mul = muls2[ir], dim = dims[ir];
    long n = 256L * mul * dim;
    for (long j = 0; j < n; ++j) nrm[j] = std_normal(g);
    long j = 0;
    for (int a0 = 0; a0 < 16; ++a0)
      for (int a1 = 0; a1 < 16; ++a1) {
        int s0 = a0 < a1 ? a0 : a1;
        int s1 = a0 < a1 ? a1 : a0;
        int t = pmap[s0][s1];
        for (int k = 0; k < mul; ++k)
          for (int i = 0; i < dim; ++i, ++j) {
            double u = g.nextd();
            if (u < 0.1) {
              float v = (float)nrm[j];
              v = v / 2.0f;
              S2[t*LD2 + cb2[ir] + k*dim + i] += (double)v;
            }
          }
      }
  }
  for (int ir = 0; ir < 4; ++ir) {
    int dim = dims[ir];
    long n = 16L * dim;
    for (long j = 0; j < n; ++j) nrm[j] = std_normal(g);
    long j = 0;
    for (int a0 = 0; a0 < 16; ++a0)
      for (int i = 0; i < dim; ++i, ++j) {
        double u = g.nextd();
        if (u < 0.1) {
          float v = (float)nrm[j];
          S1[a0*16 + cb1[ir] + i] += (double)v;
        }
      }
  }

  for (int i = 0; i < U3_FLOATS; ++i) h_U[i] = (float)S3[i];
  for (int i = 0; i < U2_FLOATS; ++i) h_U[U3_FLOATS + i] = (float)S2[i];
  for (int i = 0; i < U1_FLOATS; ++i) h_U[U3_FLOATS + U2_FLOATS + i] = (float)S1[i];
}

// ---------------------------------------------------------------------------
// Build bf16 B in chunk-major layout: h_B[(c*2+half)*256*8 + col*8 + j]
//   = bf16( U[k = c*16+half*8+j][col] ), enumeration matching TTab.
// ---------------------------------------------------------------------------
static uint16_t h_B_arr[NPAD*KPAD];
static const uint16_t* h_B_src = h_B_arr;

static inline uint16_t f2bf_h(float x) {
  uint32_t u; std::memcpy(&u, &x, 4);
  return (uint16_t)((u + 0x7fffu + ((u>>16)&1u)) >> 16);
}

static inline float Bval(int col, int k) {
  if (k < NT3)            { if (col < 149) return h_U[k*LD3 + col]; }
  else if (k < NT3+NT2)   { if (col >= 149 && col < 208) return h_U[U3_FLOATS + (k-NT3)*LD2 + (col-149)]; }
  else if (k < NT3+NT2+16){ if (col >= 208 && col < 224) return h_U[U3_FLOATS + U2_FLOATS + (k-(NT3+NT2))*16 + (col-208)]; }
  return 0.f;
}

struct UInit {
  UInit() {
    build_U();
    for (int c = 0; c < KPAD/16; ++c)
      for (int half = 0; half < 2; ++half)
        for (int col = 0; col < NPAD; ++col)
          for (int j = 0; j < 8; ++j) {
            int k = c*16 + half*8 + j;
            h_B_arr[((size_t)(c*2 + half)*NPAD + col)*8 + j] = f2bf_h(Bval(col, k));
          }
    void* p = nullptr;
    if (hipHostMalloc(&p, sizeof(h_B_arr), hipHostMallocDefault) == hipSuccess && p) {
      std::memcpy(p, h_B_arr, sizeof(h_B_arr));
      h_B_src = (const uint16_t*)p;
    }
  }
};
static UInit u_init_once;

// ---------------------------------------------------------------------------
extern "C" void kernel_launch(void* const* d_in, const int* in_sizes, int n_in,
                              void* d_out, int out_size, void* d_ws, size_t ws_size,
                              hipStream_t stream) {
  (void)in_sizes; (void)n_in; (void)d_ws; (void)ws_size; (void)out_size;

  const float* x     = (const float*)d_in[0];
  const int*   index = (const int*)d_in[1];
  const float* embed = (const float*)d_in[2];
  WPtrs wp;
  for (int i = 0; i < 12; ++i) wp.p[i] = (const float*)d_in[3 + i];

  void* bptr = nullptr;
  hipGetSymbolAddress(&bptr, HIP_SYMBOL(g_B));
  hipMemcpyAsync(bptr, h_B_src, sizeof(h_B_arr), hipMemcpyHostToDevice, stream);

  dim3 gw(NKK, NSP);
  weights_kernel<<<gw, CH, 0, stream>>>(embed, wp);
  main_kernel<<<NBATCH, 512, 0, stream>>>(x, index, (float*)d_out);
}